// Round 10
// baseline (560.144 us; speedup 1.0000x reference)
//
#include <hip/hip_runtime.h>
#include <math.h>

#define BB 256
#define TT 512
#define LL 40
#define ED 8
#define NC 22
#define HH 64
#define BLK 256   // 4 waves; 4 lanes/unit; ALL lanes do dots+GRU+eta+PK (PK redundant/wave)

#define L2E 1.4426950408889634f
#define S2E 2.8853900817779268f   // 2*log2(e)

__device__ __forceinline__ float fast_rcp(float x)  { return __builtin_amdgcn_rcpf(x); }
__device__ __forceinline__ float fast_exp2(float x) { return __builtin_amdgcn_exp2f(x); }

__device__ __forceinline__ float dpp_add_xor1(float x) {   // quad_perm [1,0,3,2]
    int v = __builtin_amdgcn_update_dpp(0, __float_as_int(x), 0xB1, 0xF, 0xF, true);
    return x + __int_as_float(v);
}
__device__ __forceinline__ float dpp_add_xor2(float x) {   // quad_perm [2,3,0,1]
    int v = __builtin_amdgcn_update_dpp(0, __float_as_int(x), 0x4E, 0xF, 0xF, true);
    return x + __int_as_float(v);
}
// sum within each aligned 4-lane quad (result in all 4 lanes)
__device__ __forceinline__ float quad_sum(float x) { return dpp_add_xor2(dpp_add_xor1(x)); }
// full wave64 all-lanes sum
__device__ __forceinline__ float wave_sum(float x) {
    int v;
    v = __builtin_amdgcn_update_dpp(0, __float_as_int(x), 0xB1, 0xF, 0xF, true);  x += __int_as_float(v);
    v = __builtin_amdgcn_update_dpp(0, __float_as_int(x), 0x4E, 0xF, 0xF, true);  x += __int_as_float(v);
    v = __builtin_amdgcn_update_dpp(0, __float_as_int(x), 0x141, 0xF, 0xF, true); x += __int_as_float(v);
    v = __builtin_amdgcn_update_dpp(0, __float_as_int(x), 0x140, 0xF, 0xF, true); x += __int_as_float(v);
    x += __shfl_xor(x, 16);
    x += __shfl_xor(x, 32);
    return x;
}

// R9 null result: role-split (8 dot waves + 1 PK wave) is spine-bound at
// ~1470 cyc/step: 2 barriers x 9 waves + vfb/eta LDS round-trips + unsplit PK.
// R10: all 4 waves compute eta+PK redundantly -> vfb is a LOCAL REGISTER,
// ONE barrier/step (double-buffered h), PK split across lane parity,
// dots(t+1) FMA stream fills the PK chain's latency stalls.
__global__
__attribute__((amdgpu_flat_work_group_size(BLK, BLK)))
__attribute__((amdgpu_waves_per_eu(1, 1)))
void scan_kernel(
    const float* __restrict__ cont, const int* __restrict__ cat,
    const float* __restrict__ lb, const int* __restrict__ mask,
    const float* __restrict__ dvec, const float* __restrict__ td,
    const float* __restrict__ emb,
    const float* __restrict__ W_ih, const float* __restrict__ W_hh,
    const float* __restrict__ b_ih, const float* __restrict__ b_hh,
    const float* __restrict__ W_out, const float* __restrict__ b_out,
    float* __restrict__ out)
{
    const int b    = blockIdx.x;
    const int tid  = threadIdx.x;
    const int lane = tid & 63;

    // feat rows: 32 floats: [0..7]=emb-sum, [8..29]=cont, [30]=0, [31]=0
    __shared__ __align__(128) float  feat[TT * 32];   // 64 KB
    __shared__ __align__(16)  float4 sc[TT];          // {d*L2E, (td24-d)*L2E, maskf, lb}
    __shared__ float  cclA[TT];
    __shared__ __align__(128) float  hbuf[2][HH];     // double-buffered h
    __shared__ __align__(16)  float  out_lds[TT];
    __shared__ float kb_lds;

    const size_t bT    = (size_t)b * TT;
    const int*   catb  = cat  + bT * LL;
    const float* contb = cont + bT * NC;

    const int j = tid >> 2;   // hidden unit 0..63
    const int s = tid & 3;    // feature quarter: dims [24s, 24s+24)

    // ---- per-lane weights: 24 per gate, prescaled for exp2 math ----
    float wr_[24], wz_[24], wn_[24];
    #pragma unroll
    for (int m = 0; m < 24; ++m) {
        const int f = 24 * s + m;
        float a, c, d;
        if (f < 30)      { a = W_ih[j*31+f]; c = W_ih[(j+64)*31+f]; d = W_ih[(j+128)*31+f]; }
        else if (f < 32) { a = 0.f; c = 0.f; d = 0.f; }   // f=30 (vfb: separate), f=31 pad
        else             { a = W_hh[j*64+f-32]; c = W_hh[(j+64)*64+f-32]; d = W_hh[(j+128)*64+f-32]; }
        wr_[m] = a * L2E;
        wz_[m] = c * L2E;
        wn_[m] = d * S2E;
    }
    #pragma unroll
    for (int m = 0; m < 24; ++m) {
        asm volatile("" : "+v"(wr_[m]));
        asm volatile("" : "+v"(wz_[m]));
        asm volatile("" : "+v"(wn_[m]));
    }
    const float br   = (b_ih[j]      + b_hh[j])      * L2E;
    const float bz   = (b_ih[j + 64] + b_hh[j + 64]) * L2E;
    const float bnx  = b_ih[j + 128] * S2E;
    const float bnh  = b_hh[j + 128] * S2E;
    const float w30r = W_ih[j * 31 + 30]         * L2E;
    const float w30z = W_ih[(j + 64) * 31 + 30]  * L2E;
    const float w30n = W_ih[(j + 128) * 31 + 30] * S2E;
    // eta: lane ell owns column ell of W_out (all 4 waves identical)
    const float wo0 = W_out[0 * HH + lane];
    const float wo1 = W_out[1 * HH + lane];
    const float wo2 = W_out[2 * HH + lane];
    const float wo3 = W_out[3 * HH + lane];
    const float boL0 = b_out[0] * L2E, boL1 = b_out[1] * L2E;
    const float boL2 = b_out[2] * L2E, boL3 = b_out[3] * L2E;

    // ---- prologue: stage block working set into LDS ----
    for (int i = tid; i < TT * NC; i += BLK) {          // cont -> feat[.][8..29]
        int r = i / NC, c = i - r * NC;
        feat[r * 32 + 8 + c] = contb[i];
    }
    for (int i = tid; i < TT; i += BLK) {               // pads
        feat[i * 32 + 30] = 0.f;
        feat[i * 32 + 31] = 0.f;
    }
    for (int i = tid; i < TT * 2; i += BLK) {           // emb gather, float4-vectorized
        int r = i >> 1, qd = i & 1;
        const int* cp = catb + r * LL;
        float4 acc = make_float4(0.f, 0.f, 0.f, 0.f);
        #pragma unroll 8
        for (int l = 0; l < LL; ++l) {
            const float4 ev = *((const float4*)(emb + cp[l] * ED) + qd);
            acc.x += ev.x; acc.y += ev.y; acc.z += ev.z; acc.w += ev.w;
        }
        ((float4*)feat)[r * 8 + qd] = acc;
    }
    for (int i = tid; i < TT; i += BLK) {               // per-step scalars (exp2-prescaled)
        float d   = dvec[bT + i];
        float t24 = td[bT + i] * 24.0f;
        sc[i] = make_float4(d * L2E, (t24 - d) * L2E, (float)mask[bT + i], lb[bT + i]);
    }
    if (tid < HH) { hbuf[0][tid] = 0.f; hbuf[1][tid] = 0.f; }
    if (tid < 64) {                                     // Kb via ballot over cat[b][0][:]
        int cv = (tid < LL) ? catb[tid] : 0;
        unsigned long long bal = __ballot(tid < LL && cv == 5);
        float g   = (float)__popcll(bal) * 0.15f + 0.85f;
        float age = contb[2]  * 16.936469f + 58.239251f;
        float wgt = contb[21] * 30.519849f + 87.5752f;
        if (tid == 0) kb_lds = (140.0f - age) * wgt * g / 72.0f;
    }
    __syncthreads();
    {
        const float Kb = kb_lds;
        for (int i = tid; i < TT; i += BLK)
            cclA[i] = Kb * fast_rcp(fmaf(contb[i * NC + 11], 1.418099f, 1.314668f));
    }

    // ---- persistent per-lane state ----
    float hreg = 0.f;                 // h_j (replicated x4 in quad)
    float vfb  = 0.f;                 // LOCAL register (PK is per-wave redundant)
    float S    = 0.f;                 // PK state: even lanes Cc, odd lanes Dc
    const float sgnC = (lane & 1) ? -1.f : 1.f;
    float sr = 0.f, sz = 0.f, snx = 0.f, snh = 0.f;

    // dots for step t: 6 conflict-free float4 LDS reads + 72 FMA + 4 quad reduces
    auto do_dots = [&](int t, const float* hb) {
        const float4* f4t = (const float4*)(feat + t * 32);
        const float4* hb4 = (const float4*)hb;
        float ra = 0.f, za = 0.f, nxa = 0.f, nha = 0.f;
        #pragma unroll
        for (int k = 0; k < 6; ++k) {
            const int idx = 6 * s + k;
            const float4 uv = (idx < 8) ? f4t[idx] : hb4[idx - 8];
            ra = fmaf(uv.x, wr_[4*k+0], ra);
            ra = fmaf(uv.y, wr_[4*k+1], ra);
            ra = fmaf(uv.z, wr_[4*k+2], ra);
            ra = fmaf(uv.w, wr_[4*k+3], ra);
            za = fmaf(uv.x, wz_[4*k+0], za);
            za = fmaf(uv.y, wz_[4*k+1], za);
            za = fmaf(uv.z, wz_[4*k+2], za);
            za = fmaf(uv.w, wz_[4*k+3], za);
            if (idx < 8) {
                nxa = fmaf(uv.x, wn_[4*k+0], nxa);
                nxa = fmaf(uv.y, wn_[4*k+1], nxa);
                nxa = fmaf(uv.z, wn_[4*k+2], nxa);
                nxa = fmaf(uv.w, wn_[4*k+3], nxa);
            } else {
                nha = fmaf(uv.x, wn_[4*k+0], nha);
                nha = fmaf(uv.y, wn_[4*k+1], nha);
                nha = fmaf(uv.z, wn_[4*k+2], nha);
                nha = fmaf(uv.w, wn_[4*k+3], nha);
            }
        }
        sr  = quad_sum(ra);
        sz  = quad_sum(za);
        snx = quad_sum(nxa);
        snh = quad_sum(nha);
    };

    do_dots(0, hbuf[1]);   // sums(0) from h(-1)=0 (buffer (-1)&1 = 1)
    __syncthreads();       // cclA visible

    for (int t = 0; t < TT; ++t) {
        // ---- GRU(t): pure registers (sums + local vfb) ----
        {
            float prer = sr + br + vfb * w30r;
            float prez = sz + bz + vfb * w30z;
            float r = fast_rcp(1.0f + fast_exp2(-prer));
            float z = fast_rcp(1.0f + fast_exp2(-prez));
            float yp = snx + bnx + vfb * w30n + r * (snh + bnh);
            float n = 1.0f - 2.0f * fast_rcp(fast_exp2(yp) + 1.0f);
            hreg = fmaf(z, hreg - n, n);
            if (s == 0) hbuf[t & 1][j] = hreg;
        }
        __syncthreads();   // h(t) visible (the ONLY barrier per step)

        const float* hb = hbuf[t & 1];

        // ---- dots(t+1): issue first so its FMA stream fills PK's latency ----
        const int tn = (t + 1 < TT) ? (t + 1) : t;
        do_dots(tn, hb);

        // ---- eta(t): 4 wave-wide butterflies from one scalar LDS read ----
        const float hv = hb[lane];
        const float e0 = wave_sum(hv * wo0);
        const float e1 = wave_sum(hv * wo1);
        const float e2 = wave_sum(hv * wo2);
        const float e3 = wave_sum(hv * wo3);

        // ---- PK(t): lane-parity split (even=C/lam1, odd=D/lam2) ----
        const float4 sv = sc[t];
        const float  cc = cclA[t];
        float E1 = fast_exp2(e0 * L2E + boL0);
        float E2 = fast_exp2(e1 * L2E + boL1);
        float E3 = fast_exp2(e2 * L2E + boL2);
        float E4 = fast_exp2(e3 * L2E + boL3);
        float v1  = 33.1f * E1;
        float rv1 = fast_rcp(v1);
        float k1  = 0.0396f * cc * E2;
        float rrr = 1000.0f * rv1;
        float v2  = 48.3f * E4;
        float R   = (-6.99f / 48.3f) * E3;
        float k2  = R * v2;
        float qq  = k1 - k2 - R * v1;
        float disc = fmaf(qq, qq, 4.0f * k1 * R * v1);
        float delta = __builtin_amdgcn_sqrtf(disc) * rv1;
        float sgm  = (k2 - k1 + R * v1) * rv1;
        float sd   = (lane & 1) ? delta : -delta;
        float lam  = (sgm + sd) * 0.5f;
        float kv   = k2 * rv1;
        float rkv  = fast_rcp(kv);
        float Cs   = sgnC * rrr * kv * fast_rcp(lam * delta);
        float Snew = fmaf(S + Cs, fast_exp2(lam * sv.x), -Cs) * fast_exp2(lam * sv.y);
        float contrib = Snew * (-(lam - R) * rkv);
        float An = dpp_add_xor1(contrib);     // Cn*C3 + Dn*C4, in all lanes
        S = Snew;
        vfb = fmaf(An, 1.0f - sv.z, sv.w * sv.z);   // vfb(t+1), LOCAL
        if (tid == 0) out_lds[t] = An;
    }

    __syncthreads();
    if (tid < TT / 4) ((float4*)(out + bT))[tid] = ((const float4*)out_lds)[tid];
}

extern "C" void kernel_launch(void* const* d_in, const int* in_sizes, int n_in,
                              void* d_out, int out_size, void* d_ws, size_t ws_size,
                              hipStream_t stream) {
    const float* cont  = (const float*)d_in[0];
    const int*   cat   = (const int*)  d_in[1];
    const float* lb    = (const float*)d_in[2];
    const int*   mask  = (const int*)  d_in[3];
    const float* dvec  = (const float*)d_in[4];
    const float* td    = (const float*)d_in[5];
    const float* emb   = (const float*)d_in[6];
    const float* W_ih  = (const float*)d_in[7];
    const float* W_hh  = (const float*)d_in[8];
    const float* b_ih  = (const float*)d_in[9];
    const float* b_hh  = (const float*)d_in[10];
    const float* W_out = (const float*)d_in[11];
    const float* b_out = (const float*)d_in[12];
    float* out = (float*)d_out;

    hipLaunchKernelGGL(scan_kernel, dim3(BB), dim3(BLK), 0, stream,
                       cont, cat, lb, mask, dvec, td, emb, W_ih, W_hh, b_ih, b_hh,
                       W_out, b_out, out);
}